// Round 4
// baseline (328.143 us; speedup 1.0000x reference)
//
#include <hip/hip_runtime.h>

// RoPE2D cos/sin table generator — float32.
// Output: [cos_2d (rows*dim)] ++ [sin_2d (rows*dim)], rows = H*W, dim = dimx+dimy.
// Row p = y*W + x. Channel c:
//   c in [0, dimx):   val = trig(x * ifx[c mod (dimx/2)])
//   c in [dimx, dim): val = trig(y * ify[(c-dimx) mod (dimy/2)])
//
// v5: single launch, one thread = matching cos-quad AND sin-quad (32 B).
// Index math + freq load amortized over 2 stores; exactly 8 trans per 32 B
// (same 4-trans/16B density as v4 but no second launch, half the threads).
// Stores are NON-TEMPORAL: falsification probe for "kernel stores run below
// fill BW due to L2 allocation thrash". If stores were already at BW this is
// neutral; if the pathology exists this recovers ~100 us.

typedef __attribute__((ext_vector_type(4))) float float4v;

// Fast path: dimx = dimy = 64 (dim = 128, half-tables of 32 floats).
// idx in [0, rows*32): one cos quad + the matching sin quad.
__global__ __launch_bounds__(256) void rope2d_pair(
    const float* __restrict__ ifx,
    const float* __restrict__ ify,
    const int* __restrict__ wptr,
    float* __restrict__ out,
    int rows)
{
    const int idx = blockIdx.x * blockDim.x + threadIdx.x;
    const int total4 = rows << 5;            // rows*128/4 quads in the cos half
    if (idx >= total4) return;

    const int e  = idx << 2;                 // element offset within cos half
    const int p  = idx >> 5;                 // row
    const int ch = e & 127;                  // first channel of the 4 (4-aligned)
    const int half = rows << 7;              // rows*128 floats

    const int W = *wptr;                     // uniform 4B load
    int xw, yh;
    if ((W & (W - 1)) == 0) {
        const int s = __ffs(W) - 1;
        xw = p & (W - 1);
        yh = p >> s;
    } else {
        xw = p % W;
        yh = p / W;
    }

    // quadrants: ch [0,64) -> x-table, [64,128) -> y-table; fidx = ch & 31
    const bool use_x = ch < 64;
    const float pos = use_x ? (float)xw : (float)yh;
    const float* tab = use_x ? ifx : ify;
    const float4v fr = *reinterpret_cast<const float4v*>(tab + (ch & 31)); // 16B, L1

    float4v vc, vs;
#pragma unroll
    for (int i = 0; i < 4; ++i) {
        const float f = pos * fr[i];
        vc[i] = __cosf(f);
        vs[i] = __sinf(f);
    }

    // Two dense, lane-contiguous dwordx4 streams; non-temporal (bypass L2).
    __builtin_nontemporal_store(vc, reinterpret_cast<float4v*>(out + e));
    __builtin_nontemporal_store(vs, reinterpret_cast<float4v*>(out + half + e));
}

// Generic path: arbitrary dimx/dimy (scalar per element, one-shot).
__global__ __launch_bounds__(256) void rope2d_generic(
    const float* __restrict__ ifx,
    const float* __restrict__ ify,
    const int* __restrict__ wptr,
    float* __restrict__ out,
    int rows, int dimx, int dimy)
{
    const int dim = dimx + dimy;
    const long long total = 2LL * rows * dim;
    const long long e = (long long)(blockIdx.x * blockDim.x + threadIdx.x);
    if (e >= total) return;

    const long long halfo = (long long)rows * dim;
    const bool is_sin = e >= halfo;
    const long long e2 = is_sin ? e - halfo : e;
    const int p  = (int)(e2 / dim);
    const int ch = (int)(e2 % dim);

    const int W = *wptr;
    const int xw = p % W, yh = p / W;

    float pos, f;
    if (ch < dimx) { pos = (float)xw; f = ifx[ch % (dimx >> 1)]; }
    else           { pos = (float)yh; f = ify[(ch - dimx) % (dimy >> 1)]; }
    const float ang = pos * f;
    out[e] = is_sin ? __sinf(ang) : __cosf(ang);
}

extern "C" void kernel_launch(void* const* d_in, const int* in_sizes, int n_in,
                              void* d_out, int out_size, void* d_ws, size_t ws_size,
                              hipStream_t stream) {
    // inputs: [0]=x (f32, dtype-only), [1]=inv_freq_x (f32), [2]=inv_freq_y (f32),
    //         [3]=height (int32), [4]=width (int32)
    const float* ifx = (const float*)d_in[1];
    const float* ify = (const float*)d_in[2];
    const int* wptr  = (const int*)d_in[4];
    float* out = (float*)d_out;

    const int dimx = 2 * in_sizes[1];      // 64
    const int dimy = 2 * in_sizes[2];      // 64
    const int dim  = dimx + dimy;          // 128
    const int rows = in_sizes[0] / dim;    // H*W = 262144

    const int block = 256;

    if (dimx == 64 && dimy == 64) {
        const int total4 = rows << 5;                      // 8,388,608 paired quads
        const int grid = (total4 + block - 1) / block;     // 32,768 blocks
        rope2d_pair<<<grid, block, 0, stream>>>(ifx, ify, wptr, out, rows);
    } else {
        const long long total = 2LL * rows * dim;
        const long long grid = (total + block - 1) / block;
        rope2d_generic<<<(int)grid, block, 0, stream>>>(ifx, ify, wptr, out,
                                                        rows, dimx, dimy);
    }
}

// Round 5
// 321.120 us; speedup vs baseline: 1.0219x; 1.0219x over previous
//
#include <hip/hip_runtime.h>

// RoPE2D cos/sin table generator — float32, fully dense store mapping.
// Output: [cos_2d (rows*dim)] ++ [sin_2d (rows*dim)], rows = H*W, dim = dimx+dimy.
// Row p = y*W + x. Channel c:
//   c in [0, dimx):   val = trig(x * ifx[c mod (dimx/2)])
//   c in [dimx, dim): val = trig(y * ify[(c-dimx) mod (dimy/2)])
// One thread = 4 contiguous output floats -> single lane-contiguous dwordx4 store.
//
// FINAL (r5 = revert to best-measured r0/r1 structure, 320.3 us):
// Store-roofline-bound. Evidence ledger across 5 benched variants:
//   r0/r1 this kernel            321.3 / 320.3 us  (repeat noise +-1 us)
//   r2 grid-stride 2048 blocks   339.2  (latency-bound, too few waves)
//   r3 split cos/sin launches    324.9  (launch tax, trans cut bought 0)
//   r4 paired 32B + nt stores    328.1  (L2-bypass slightly hurts; no thrash)
// Arithmetic: 268 MB mandatory writes @ ~6.5 TB/s (fill-demonstrated) ~ 43 us
// kernel floor; compute side ~13 us (8 predicated trans + ~30 VALU per 16 B).
// No compute change ever moved dur_us -> store-bound. Remaining bench time is
// harness-fixed (poison fill ~165 us + reset dispatches).

typedef __attribute__((ext_vector_type(4))) float float4v;

// Fast path: dimx = dimy = 64 (dim = 128, half-tables of 32). fidx = ch & 31 for both halves.
__global__ __launch_bounds__(256) void rope2d_fast(
    const float* __restrict__ ifx,
    const float* __restrict__ ify,
    const int* __restrict__ wptr,
    float* __restrict__ out,
    int rows)
{
    const int idx = blockIdx.x * blockDim.x + threadIdx.x;
    const int total4 = rows << 6;            // 2*rows*128/4
    if (idx >= total4) return;

    const int e = idx << 2;                  // element offset in flat output
    const int half = rows << 7;              // rows*128
    const bool is_sin = e >= half;           // wave-uniform (half % 256 == 0 when rows even)
    const int e2 = is_sin ? e - half : e;

    const int p  = e2 >> 7;                  // row
    const int ch = e2 & 127;                 // channel of first of 4 (4-aligned)

    const int W = *wptr;
    int xw, yh;
    if ((W & (W - 1)) == 0) {
        const int s = __ffs(W) - 1;
        xw = p & (W - 1);
        yh = p >> s;
    } else {
        xw = p % W;
        yh = p / W;
    }

    // channel quadrant: [0,64) -> x-table, [64,128) -> y-table; fidx = ch & 31 either way
    const bool use_x = ch < 64;
    const float pos = use_x ? (float)xw : (float)yh;
    const float* tab = use_x ? ifx : ify;
    const float4v fr = *reinterpret_cast<const float4v*>(tab + (ch & 31)); // 16B, L1-resident

    float4v v;
#pragma unroll
    for (int i = 0; i < 4; ++i) {
        const float f = pos * fr[i];
        v[i] = is_sin ? __sinf(f) : __cosf(f);   // v_sin/v_cos, wave-uniform select
    }

    *reinterpret_cast<float4v*>(out + e) = v;    // dense dwordx4, lanes contiguous
}

// Generic path: arbitrary dimx/dimy (scalar per element).
__global__ __launch_bounds__(256) void rope2d_generic(
    const float* __restrict__ ifx,
    const float* __restrict__ ify,
    const int* __restrict__ wptr,
    float* __restrict__ out,
    int rows, int dimx, int dimy)
{
    const int dim = dimx + dimy;
    const long long total = 2LL * rows * dim;
    const long long e = (long long)(blockIdx.x * blockDim.x + threadIdx.x);
    if (e >= total) return;

    const long long halfo = (long long)rows * dim;
    const bool is_sin = e >= halfo;
    const long long e2 = is_sin ? e - halfo : e;
    const int p  = (int)(e2 / dim);
    const int ch = (int)(e2 % dim);

    const int W = *wptr;
    const int xw = p % W, yh = p / W;

    float pos, f;
    if (ch < dimx) { pos = (float)xw; f = ifx[ch % (dimx >> 1)]; }
    else           { pos = (float)yh; f = ify[(ch - dimx) % (dimy >> 1)]; }
    const float ang = pos * f;
    out[e] = is_sin ? __sinf(ang) : __cosf(ang);
}

extern "C" void kernel_launch(void* const* d_in, const int* in_sizes, int n_in,
                              void* d_out, int out_size, void* d_ws, size_t ws_size,
                              hipStream_t stream) {
    // inputs: [0]=x (f32, dtype-only), [1]=inv_freq_x (f32), [2]=inv_freq_y (f32),
    //         [3]=height (int32), [4]=width (int32)
    const float* ifx = (const float*)d_in[1];
    const float* ify = (const float*)d_in[2];
    const int* wptr  = (const int*)d_in[4];
    float* out = (float*)d_out;

    const int dimx = 2 * in_sizes[1];      // 64
    const int dimy = 2 * in_sizes[2];      // 64
    const int dim  = dimx + dimy;          // 128
    const int rows = in_sizes[0] / dim;    // H*W = 262144

    if (dimx == 64 && dimy == 64) {
        const int total4 = rows << 6;                      // 16,777,216 threads
        const int block = 256;
        const int grid = (total4 + block - 1) / block;     // 65,536
        rope2d_fast<<<grid, block, 0, stream>>>(ifx, ify, wptr, out, rows);
    } else {
        const long long total = 2LL * rows * dim;
        const int block = 256;
        const int grid = (int)((total + block - 1) / block);
        rope2d_generic<<<grid, block, 0, stream>>>(ifx, ify, wptr, out, rows, dimx, dimy);
    }
}